// Round 12
// baseline (238.714 us; speedup 1.0000x reference)
//
#include <hip/hip_runtime.h>

#define NN 50000
#define NE 800000
#define HID 128
#define NG 128
#define NOUT 10
#define FEAT 512   // 128*3 + 128
#define BN_EPS 1e-5f
#define NTILE (NN / 16)         // 3125 node-tiles
#define NBKT 256                // dst>>8 buckets (196 live)
#define NBB  ((NN + 255) / 256) // 196 bucket blocks
#define EPB 4096                // edges per scatter block
#define NSB ((NE + EPB - 1) / EPB) // 196 scatter blocks
#define CAPB 6144               // fixed per-bucket region
#define CAP 8192                // LDS stage capacity

typedef __attribute__((ext_vector_type(8))) short bf16x8;
typedef __attribute__((ext_vector_type(4))) float f32x4;

__device__ __forceinline__ void add4(float4& a, const float4& v) {
    a.x += v.x; a.y += v.y; a.z += v.z; a.w += v.w;
}
__device__ __forceinline__ unsigned short f2bf(float f) {
    unsigned int u = __float_as_uint(f);
    u += 0x7FFFu + ((u >> 16) & 1u);
    return (unsigned short)(u >> 16);
}
__device__ __forceinline__ float bf2f(unsigned int h) {
    return __uint_as_float(h << 16);
}
__device__ __forceinline__ int lbound(const int* __restrict__ b, int n, int v) {
    int lo = 0, hi = n;
    while (lo < hi) { int mid = (lo + hi) >> 1; if (b[mid] < v) lo = mid + 1; else hi = mid; }
    return lo;
}

// ================= prep: W transpose->bf16, zero bh, zero pooled =================
__global__ __launch_bounds__(256) void k_prep(const float* __restrict__ Ws,
        unsigned short* __restrict__ Wt, int* __restrict__ bh, float* __restrict__ pooled)
{
    const int b = blockIdx.x;
    if (b < 24) {
        int g0 = b * 2048 + threadIdx.x * 8;
#pragma unroll
        for (int j = 0; j < 8; ++j) {
            int idx = g0 + j;
            int l = idx >> 14, rem = idx & 16383;
            int c = rem >> 7, k = rem & 127;
            Wt[idx] = f2bf(Ws[l * 16384 + k * 128 + c]);
        }
    } else if (b == 24) {
        bh[threadIdx.x] = 0;
    } else {
        float4* p = (float4*)pooled;
        int i0 = (b - 25) * 8192 + threadIdx.x;
        for (int i = i0; i < (b - 25) * 8192 + 8192; i += 256)
            p[i] = make_float4(0.f, 0.f, 0.f, 0.f);
    }
}

// ================= bucketed CSR build =================
__global__ __launch_bounds__(256) void k_scatter(const int* __restrict__ ei,
        int* __restrict__ bh, unsigned int* __restrict__ bucketed) {
    __shared__ int bcnt[NBKT];
    __shared__ int gbase[NBKT];
    const int t = threadIdx.x;
    bcnt[t] = 0;
    __syncthreads();
    const int e0 = blockIdx.x * EPB;
#pragma unroll
    for (int i = 0; i < EPB / 256; ++i) {
        int e = e0 + i * 256 + t;
        if (e < NE) atomicAdd(&bcnt[ei[NE + e] >> 8], 1);
    }
    __syncthreads();
    if (bcnt[t]) gbase[t] = atomicAdd(&bh[t], bcnt[t]);
    __syncthreads();
    bcnt[t] = 0;
    __syncthreads();
#pragma unroll
    for (int i = 0; i < EPB / 256; ++i) {
        int e = e0 + i * 256 + t;
        if (e < NE) {
            int dst = ei[NE + e], src = ei[e];
            int bkt = dst >> 8;
            int r = atomicAdd(&bcnt[bkt], 1);
            bucketed[bkt * CAPB + gbase[bkt] + r] = ((unsigned)(dst & 255) << 16) | (unsigned)src;
        }
    }
}

// per bucket: derive wbase via in-block scan of bh; count+scan dsts -> rowptr/dinv;
// stage csr segment in LDS, write coalesced at dense offset.
__global__ __launch_bounds__(256) void k_bucket_csr(const unsigned int* __restrict__ bucketed,
        const int* __restrict__ bh, unsigned short* __restrict__ csr,
        int* __restrict__ rowptr, float* __restrict__ dinv) {
    __shared__ int cnt[NBKT];
    __shared__ int cur[NBKT];
    __shared__ unsigned short stage[CAP];
    const int b = blockIdx.x;
    const int t = threadIdx.x;
    // ---- fused hscan: wbase = sum bh[0..b) ----
    cnt[t] = bh[t];
    __syncthreads();
    for (int off = 1; off < NBKT; off <<= 1) {
        int a = (t >= off) ? cnt[t - off] : 0;
        __syncthreads();
        cnt[t] += a;
        __syncthreads();
    }
    const int wbase = (b == 0) ? 0 : cnt[b - 1];
    const int n = bh[b];
    const int rbase = b * CAPB;
    __syncthreads();
    // ---- per-dst count ----
    cnt[t] = 0;
    __syncthreads();
    for (int i = t; i < n; i += 256) atomicAdd(&cnt[bucketed[rbase + i] >> 16], 1);
    __syncthreads();
    int v = cnt[t];
    cur[t] = v;
    __syncthreads();
    for (int off = 1; off < NBKT; off <<= 1) {
        int a = (t >= off) ? cur[t - off] : 0;
        __syncthreads();
        cur[t] += a;
        __syncthreads();
    }
    int excl = cur[t] - v;
    int d = b * 256 + t;
    if (d < NN) {
        rowptr[d] = wbase + excl;
        dinv[d] = rsqrtf((float)v + 1.0f);   // +1 self-loop
    }
    if (d == NN) rowptr[NN] = NE;
    __syncthreads();
    cur[t] = excl;
    __syncthreads();
    if (n <= CAP) {
        for (int i = t; i < n; i += 256) {
            unsigned p = bucketed[rbase + i];
            int r = atomicAdd(&cur[p >> 16], 1);
            stage[r] = (unsigned short)(p & 0xFFFFu);
        }
        __syncthreads();
        for (int i = t; i < n; i += 256) csr[wbase + i] = stage[i];
    } else {  // paranoia fallback (never taken for this input)
        for (int i = t; i < n; i += 256) {
            unsigned p = bucketed[rbase + i];
            int r = atomicAdd(&cur[p >> 16], 1);
            csr[wbase + r] = (unsigned short)(p & 0xFFFFu);
        }
    }
}

// ---- shared device helpers ----
__device__ __forceinline__ int swz(int row, int col16B) {
    return (row * 256 + col16B * 16) ^ ((row & 7) << 4);
}

__device__ __forceinline__ void accinit(float* a, uint4 v) {
    a[0] = bf2f(v.x & 0xFFFFu); a[1] = bf2f(v.x >> 16);
    a[2] = bf2f(v.y & 0xFFFFu); a[3] = bf2f(v.y >> 16);
    a[4] = bf2f(v.z & 0xFFFFu); a[5] = bf2f(v.z >> 16);
    a[6] = bf2f(v.w & 0xFFFFu); a[7] = bf2f(v.w >> 16);
}
__device__ __forceinline__ void acc8(float* a, uint4 v) {
    a[0] += bf2f(v.x & 0xFFFFu); a[1] += bf2f(v.x >> 16);
    a[2] += bf2f(v.y & 0xFFFFu); a[3] += bf2f(v.y >> 16);
    a[4] += bf2f(v.z & 0xFFFFu); a[5] += bf2f(v.z >> 16);
    a[6] += bf2f(v.w & 0xFFFFu); a[7] += bf2f(v.w >> 16);
}

// 8-deep unrolled row gather; NT index loads (read-once streams must not evict A-rows)
__device__ __forceinline__ void gather_rows(const uint4* __restrict__ A4,
        const unsigned short* __restrict__ csr, int e, int e1, int l16, float* acc)
{
    for (; e + 7 < e1; e += 8) {
        int s0 = __builtin_nontemporal_load(&csr[e]);
        int s1 = __builtin_nontemporal_load(&csr[e + 1]);
        int s2 = __builtin_nontemporal_load(&csr[e + 2]);
        int s3 = __builtin_nontemporal_load(&csr[e + 3]);
        int s4 = __builtin_nontemporal_load(&csr[e + 4]);
        int s5 = __builtin_nontemporal_load(&csr[e + 5]);
        int s6 = __builtin_nontemporal_load(&csr[e + 6]);
        int s7 = __builtin_nontemporal_load(&csr[e + 7]);
        uint4 v0 = A4[s0 * 16 + l16];
        uint4 v1 = A4[s1 * 16 + l16];
        uint4 v2 = A4[s2 * 16 + l16];
        uint4 v3 = A4[s3 * 16 + l16];
        uint4 v4 = A4[s4 * 16 + l16];
        uint4 v5 = A4[s5 * 16 + l16];
        uint4 v6 = A4[s6 * 16 + l16];
        uint4 v7 = A4[s7 * 16 + l16];
        acc8(acc, v0); acc8(acc, v1); acc8(acc, v2); acc8(acc, v3);
        acc8(acc, v4); acc8(acc, v5); acc8(acc, v6); acc8(acc, v7);
    }
    for (; e + 3 < e1; e += 4) {
        int s0 = __builtin_nontemporal_load(&csr[e]);
        int s1 = __builtin_nontemporal_load(&csr[e + 1]);
        int s2 = __builtin_nontemporal_load(&csr[e + 2]);
        int s3 = __builtin_nontemporal_load(&csr[e + 3]);
        uint4 v0 = A4[s0 * 16 + l16];
        uint4 v1 = A4[s1 * 16 + l16];
        uint4 v2 = A4[s2 * 16 + l16];
        uint4 v3 = A4[s3 * 16 + l16];
        acc8(acc, v0); acc8(acc, v1); acc8(acc, v2); acc8(acc, v3);
    }
    for (; e < e1; ++e) acc8(acc, A4[__builtin_nontemporal_load(&csr[e]) * 16 + l16]);
}

__device__ __forceinline__ void bn_relu(const float* acc, float di, int c0,
        const float* __restrict__ bs, const float* __restrict__ gam,
        const float* __restrict__ bet, const float* __restrict__ rm,
        const float* __restrict__ rv, float* o)
{
    float4 g0 = *(const float4*)&gam[c0], g1 = *(const float4*)&gam[c0 + 4];
    float4 r0 = *(const float4*)&rv[c0],  r1 = *(const float4*)&rv[c0 + 4];
    float4 b0 = *(const float4*)&bs[c0],  b1 = *(const float4*)&bs[c0 + 4];
    float4 m0 = *(const float4*)&rm[c0],  m1 = *(const float4*)&rm[c0 + 4];
    float4 e0 = *(const float4*)&bet[c0], e1v = *(const float4*)&bet[c0 + 4];
    float gg[8] = {g0.x, g0.y, g0.z, g0.w, g1.x, g1.y, g1.z, g1.w};
    float rr[8] = {r0.x, r0.y, r0.z, r0.w, r1.x, r1.y, r1.z, r1.w};
    float bb[8] = {b0.x, b0.y, b0.z, b0.w, b1.x, b1.y, b1.z, b1.w};
    float mm[8] = {m0.x, m0.y, m0.z, m0.w, m1.x, m1.y, m1.z, m1.w};
    float ee[8] = {e0.x, e0.y, e0.z, e0.w, e1v.x, e1v.y, e1v.z, e1v.w};
#pragma unroll
    for (int j = 0; j < 8; ++j) {
        float sc = gg[j] * rsqrtf(rr[j] + BN_EPS);
        o[j] = fmaxf((acc[j] * di + bb[j] - mm[j]) * sc + ee[j], 0.f);
    }
}

// GEMM tile; output written with NT stores (never re-read on this XCD)
__device__ __forceinline__ void tile_gemm(const unsigned short* __restrict__ sh,
        const unsigned short* __restrict__ Wt, const float* __restrict__ dinv,
        unsigned short* __restrict__ Aout, int rbase, int w, int lane)
{
    const int lr = lane & 15;
    const int kg = lane >> 4;
    bf16x8 af[4];
#pragma unroll
    for (int s = 0; s < 4; ++s) {
        int b = (lr * 256 + kg * 16 + s * 64) ^ ((lr & 7) << 4);
        af[s] = *(const bf16x8*)((const char*)sh + b);
    }
    const float4 dv = *(const float4*)&dinv[rbase + kg * 4];
    const float dvj[4] = {dv.x, dv.y, dv.z, dv.w};
#pragma unroll
    for (int cti = 0; cti < 2; ++cti) {
        const int ct = w * 2 + cti;
        const unsigned short* wrow = Wt + (size_t)(ct * 16 + lr) * HID + kg * 8;
        f32x4 acc = {0.f, 0.f, 0.f, 0.f};
#pragma unroll
        for (int s = 0; s < 4; ++s) {
            bf16x8 bf = *(const bf16x8*)(wrow + s * 32);
            acc = __builtin_amdgcn_mfma_f32_16x16x32_bf16(af[s], bf, acc, 0, 0, 0);
        }
#pragma unroll
        for (int j = 0; j < 4; ++j)
            __builtin_nontemporal_store(f2bf(acc[j] * dvj[j]),
                &Aout[(size_t)(rbase + kg * 4 + j) * HID + ct * 16 + lr]);
    }
}

__device__ __forceinline__ void pool_combine(const float4 (*po)[32], const int* bid,
        float* __restrict__ pooled, int tid)
{
    if (tid < 32) {
#pragma unroll
        for (int i = 0; i < 16; ++i) {
            bool lead = true;
            for (int j = 0; j < i; ++j) lead = lead && (bid[j] != bid[i]);
            if (lead) {
                float4 s = po[i][tid];
                for (int j = i + 1; j < 16; ++j)
                    if (bid[j] == bid[i]) add4(s, po[j][tid]);
                float* p = &pooled[bid[i] * FEAT + tid * 4];
                atomicAdd(p + 0, s.x);
                atomicAdd(p + 1, s.y);
                atomicAdd(p + 2, s.z);
                atomicAdd(p + 3, s.w);
            }
        }
    }
}

// ================= fused: x pool + x->bf16 + gemm W0 -> M =================
__global__ __launch_bounds__(256) void k_x_gemm(const float* __restrict__ x,
        const int* __restrict__ batch, const unsigned short* __restrict__ Wt,
        const float* __restrict__ dinv, float* __restrict__ pooled,
        unsigned short* __restrict__ M)
{
    __shared__ __align__(16) unsigned short sh[16 * 128];
    __shared__ float4 po[16][32];
    __shared__ int bid[16];
    const int t = threadIdx.x;
    const int w = t >> 6;
    const int lane = t & 63;
    const int grp = lane >> 4;
    const int l16 = lane & 15;
    const int nloc = w * 4 + grp;
    const int n = blockIdx.x * 16 + nloc;

    const float4* xr = (const float4*)(x + (size_t)n * HID + l16 * 8);
    float4 a = xr[0], b = xr[1];
    uint4 ob;
    ob.x = (unsigned)f2bf(a.x) | ((unsigned)f2bf(a.y) << 16);
    ob.y = (unsigned)f2bf(a.z) | ((unsigned)f2bf(a.w) << 16);
    ob.z = (unsigned)f2bf(b.x) | ((unsigned)f2bf(b.y) << 16);
    ob.w = (unsigned)f2bf(b.z) | ((unsigned)f2bf(b.w) << 16);
    *(uint4*)((char*)sh + swz(nloc, l16)) = ob;
    po[nloc][l16 * 2]     = a;
    po[nloc][l16 * 2 + 1] = b;
    if (l16 == 0) bid[nloc] = batch[n];
    __syncthreads();

    tile_gemm(sh, Wt, dinv, M, blockIdx.x * 16, w, lane);
    pool_combine(po, bid, pooled, t);
}

// ================= fused: aggregate + BN/ReLU + pool + gemm W_{L+1} -> Mout =================
__global__ __launch_bounds__(256) void k_aggemm(const unsigned short* __restrict__ Ain,
        const int* __restrict__ rowptr, const unsigned short* __restrict__ csr,
        const float* __restrict__ dinv, const float* __restrict__ bs,
        const float* __restrict__ gam, const float* __restrict__ bet,
        const float* __restrict__ rm, const float* __restrict__ rv,
        const int* __restrict__ batch, float* __restrict__ pooled,
        const unsigned short* __restrict__ Wt, unsigned short* __restrict__ Mout)
{
    __shared__ __align__(16) unsigned short sh[16 * 128];
    __shared__ float4 po[16][32];
    __shared__ int bid[16];
    const int t = threadIdx.x;
    const int w = t >> 6;
    const int lane = t & 63;
    const int grp = lane >> 4;
    const int l16 = lane & 15;
    const int nloc = w * 4 + grp;
    const int d = blockIdx.x * 16 + nloc;
    const uint4* __restrict__ A4 = (const uint4*)Ain;

    float acc[8];
    accinit(acc, A4[d * 16 + l16]);                 // self-loop term
    gather_rows(A4, csr, rowptr[d], rowptr[d + 1], l16, acc);

    float o[8];
    bn_relu(acc, dinv[d], l16 * 8, bs, gam, bet, rm, rv, o);

    uint4 ob;
    ob.x = (unsigned)f2bf(o[0]) | ((unsigned)f2bf(o[1]) << 16);
    ob.y = (unsigned)f2bf(o[2]) | ((unsigned)f2bf(o[3]) << 16);
    ob.z = (unsigned)f2bf(o[4]) | ((unsigned)f2bf(o[5]) << 16);
    ob.w = (unsigned)f2bf(o[6]) | ((unsigned)f2bf(o[7]) << 16);
    *(uint4*)((char*)sh + swz(nloc, l16)) = ob;
    po[nloc][l16 * 2]     = make_float4(o[0], o[1], o[2], o[3]);
    po[nloc][l16 * 2 + 1] = make_float4(o[4], o[5], o[6], o[7]);
    if (l16 == 0) bid[nloc] = batch[d];
    __syncthreads();

    tile_gemm(sh, Wt, dinv, Mout, blockIdx.x * 16, w, lane);
    pool_combine(po, bid, pooled, t);
}

// ================= last layer: aggregate + BN/ReLU + pool only =================
__global__ __launch_bounds__(256) void k_agg3(const unsigned short* __restrict__ Ain,
        const int* __restrict__ rowptr, const unsigned short* __restrict__ csr,
        const float* __restrict__ dinv, const float* __restrict__ bs,
        const float* __restrict__ gam, const float* __restrict__ bet,
        const float* __restrict__ rm, const float* __restrict__ rv,
        const int* __restrict__ batch, float* __restrict__ pooled)
{
    __shared__ float4 po[16][32];
    __shared__ int bid[16];
    const int t = threadIdx.x;
    const int w = t >> 6;
    const int lane = t & 63;
    const int grp = lane >> 4;
    const int l16 = lane & 15;
    const int nloc = w * 4 + grp;
    const int d = blockIdx.x * 16 + nloc;
    const uint4* __restrict__ A4 = (const uint4*)Ain;

    float acc[8];
    accinit(acc, A4[d * 16 + l16]);                 // self-loop term
    gather_rows(A4, csr, rowptr[d], rowptr[d + 1], l16, acc);

    float o[8];
    bn_relu(acc, dinv[d], l16 * 8, bs, gam, bet, rm, rv, o);

    po[nloc][l16 * 2]     = make_float4(o[0], o[1], o[2], o[3]);
    po[nloc][l16 * 2 + 1] = make_float4(o[4], o[5], o[6], o[7]);
    if (l16 == 0) bid[nloc] = batch[d];
    __syncthreads();
    pool_combine(po, bid, pooled, t);
}

// ---- classifier + log_softmax ----
__global__ void k_final(const float* __restrict__ pooled, const int* __restrict__ batch,
        const float* __restrict__ Wc, const float* __restrict__ bc, float* __restrict__ out)
{
    __shared__ float lg[NOUT];
    int g = blockIdx.x;
    int t = threadIdx.x;  // 64
    int start = lbound(batch, NN, g);
    int end = lbound(batch, NN, g + 1);
    float inv = 1.f / fmaxf((float)(end - start), 1.f);
    if (t < NOUT) {
        float acc = bc[t];
        for (int c = 0; c < FEAT; ++c)
            acc = fmaf(pooled[g * FEAT + c] * inv, Wc[c * NOUT + t], acc);
        lg[t] = acc;
    }
    __syncthreads();
    if (t == 0) {
        float m = -1e30f;
        for (int o = 0; o < NOUT; ++o) m = fmaxf(m, lg[o]);
        float ssum = 0.f;
        for (int o = 0; o < NOUT; ++o) ssum += expf(lg[o] - m);
        float lse = m + logf(ssum);
        for (int o = 0; o < NOUT; ++o) out[g * NOUT + o] = lg[o] - lse;
    }
}

extern "C" void kernel_launch(void* const* d_in, const int* in_sizes, int n_in,
                              void* d_out, int out_size, void* d_ws, size_t ws_size,
                              hipStream_t stream)
{
    const float* x      = (const float*)d_in[0];
    const int*   ei     = (const int*)d_in[1];
    const int*   batch  = (const int*)d_in[2];
    const float* Ws     = (const float*)d_in[3];
    const float* bs     = (const float*)d_in[4];
    const float* gammas = (const float*)d_in[5];
    const float* betas  = (const float*)d_in[6];
    const float* rms    = (const float*)d_in[7];
    const float* rvs    = (const float*)d_in[8];
    const float* Wc     = (const float*)d_in[9];
    const float* bc     = (const float*)d_in[10];
    float* out = (float*)d_out;

    float*          dinv     = (float*)d_ws;                   // NN
    float*          pooled   = dinv + NN;                      // NG*FEAT
    unsigned short* M        = (unsigned short*)(pooled + NG * FEAT);  // NN*HID bf16
    unsigned short* M2       = M + (size_t)NN * HID;           // NN*HID bf16
    unsigned short* Wt       = M2 + (size_t)NN * HID;          // 3*HID*HID bf16
    int*            rowptr   = (int*)(Wt + 3 * HID * HID);     // NN+1
    int*            bh       = rowptr + NN + 1;                // NBKT
    unsigned int*   bucketed = (unsigned int*)(bh + NBKT);     // NBKT*CAPB
    unsigned short* csr      = (unsigned short*)(bucketed + (size_t)NBKT * CAPB); // NE

    // prep: W transpose + zero bh + zero pooled
    k_prep<<<27, 256, 0, stream>>>(Ws, Wt, bh, pooled);

    // bucketed CSR build (once; reused for all 3 layers)
    k_scatter<<<NSB, 256, 0, stream>>>(ei, bh, bucketed);
    k_bucket_csr<<<NBB, 256, 0, stream>>>(bucketed, bh, csr, rowptr, dinv);

    // layer pipeline (B never materialized)
    k_x_gemm<<<NTILE, 256, 0, stream>>>(x, batch, Wt, dinv, pooled, M);
    k_aggemm<<<NTILE, 256, 0, stream>>>(M, rowptr, csr, dinv,
        bs, gammas, betas, rms, rvs, batch, pooled + 1 * HID,
        Wt + 1 * HID * HID, M2);
    k_aggemm<<<NTILE, 256, 0, stream>>>(M2, rowptr, csr, dinv,
        bs + HID, gammas + HID, betas + HID, rms + HID, rvs + HID,
        batch, pooled + 2 * HID, Wt + 2 * HID * HID, M);
    k_agg3<<<NTILE, 256, 0, stream>>>(M, rowptr, csr, dinv,
        bs + 2 * HID, gammas + 2 * HID, betas + 2 * HID, rms + 2 * HID, rvs + 2 * HID,
        batch, pooled + 3 * HID);

    k_final<<<NG, 64, 0, stream>>>(pooled, batch, Wc, bc, out);
}